// Round 16
// baseline (183.168 us; speedup 1.0000x reference)
//
#include <hip/hip_runtime.h>
#include <hip/hip_bf16.h>

typedef unsigned short u16;
typedef unsigned int   u32;

typedef __bf16 bf16x8 __attribute__((ext_vector_type(8)));
typedef float  f32x4  __attribute__((ext_vector_type(4)));

#define MFMA16(A, B, C) __builtin_amdgcn_mfma_f32_16x16x32_bf16(A, B, C, 0, 0, 0)

static __device__ __forceinline__ u16 f2bf(float f) {
  union { float f; u32 u; } v; v.f = f;
  u32 r = v.u + 0x7fffu + ((v.u >> 16) & 1u);
  return (u16)(r >> 16);
}

static __device__ __forceinline__ float exp2a(float x) {  // 2^x, raw v_exp_f32
  float r; asm("v_exp_f32 %0, %1" : "=v"(r) : "v"(x)); return r;
}
static __device__ __forceinline__ float max3f(float a, float b, float c) {
  float r; asm("v_max3_f32 %0, %1, %2, %3" : "=v"(r) : "v"(a), "v"(b), "v"(c)); return r;
}
static __device__ __forceinline__ u32 cvtpk(float lo, float hi) {  // {bf16(lo), bf16(hi)}
  u32 r; asm("v_cvt_pk_bf16_f32 %0, %1, %2" : "=v"(r) : "v"(lo), "v"(hi)); return r;
}

static __device__ __forceinline__ void async16(const void* g, void* l) {
  __builtin_amdgcn_global_load_lds((const __attribute__((address_space(1))) void*)g,
                                   (__attribute__((address_space(3))) void*)l, 16, 0, 0);
}

// slot-swizzle involution (16B granularity) for 128B-row LDS tiles
static __device__ __forceinline__ int permrow(int r) {
  return (r & 3) | (((r >> 3) & 1) << 2);
}

// ---------------- prep: x fp32->bf16 (blocks 0..8191) + W transpose (8192..12287) ----
__global__ __launch_bounds__(256) void prep_k(const float* __restrict__ x, u16* __restrict__ xb,
                                              const float* __restrict__ Wq, const float* __restrict__ Wk,
                                              const float* __restrict__ Wv, const float* __restrict__ Wo,
                                              u16* __restrict__ WT) {
  __shared__ float tile[32][33];
  const int bid = blockIdx.x;
  if (bid < 8192) {
    size_t i = ((size_t)bid * 256 + threadIdx.x) * 4;
    float4 v = *(const float4*)(x + i);
    u32 lo = (u32)f2bf(v.x) | ((u32)f2bf(v.y) << 16);
    u32 hi = (u32)f2bf(v.z) | ((u32)f2bf(v.w) << 16);
    *(uint2*)(xb + i) = make_uint2(lo, hi);
  } else {
    const int rem = bid - 8192;
    const int z = rem >> 10;
    const int rr = rem & 1023;
    const int n0 = (rr & 31) * 32;
    const int k0 = (rr >> 5) * 32;
    const float* W = (z == 0) ? Wq : (z == 1) ? Wk : (z == 2) ? Wv : Wo;
    u16* out = WT + (size_t)z * 1048576;
    const int tx = threadIdx.x & 31, ty = threadIdx.x >> 5;
#pragma unroll
    for (int i = 0; i < 4; i++)
      tile[ty + i * 8][tx] = W[(size_t)(k0 + ty + i * 8) * 1024 + n0 + tx];
    __syncthreads();
#pragma unroll
    for (int i = 0; i < 4; i++)
      out[(size_t)(n0 + ty + i * 8) * 1024 + k0 + tx] = f2bf(tile[tx][ty + i * 8]);
  }
}

// ---------------- GEMM qg8: 128x256 tile, BK=64, 4 waves x (128x64), 3-phase ring-3 ----
// Parts per K-tile: A halves P0/P1 (64x64, 2 gloads/thr), B halves N0/N1
// (128x64, 4 gloads/thr). LDS ring-3 per operand (As 3x8KB, Bs 3x16KB = 72KB
// -> 2 blocks/CU). Tile t: P0,N0 in slot SA=(2t)%3; P1,N1 in SB=(2t+1)%3.
// Phases (per-phase: counted vmcnt -> raw barrier -> stage -> ds_read -> MFMA):
//  ph0: vmcnt(6)  stage P0(t+1)->SC       read A-P0,B-N0[SA]  MFMA mf0-3 x nf0-1
//  ph1: vmcnt(2)  stage N0(t+1)->SC       read B-N1[SB]       MFMA mf0-3 x nf2-3
//  ph2: vmcnt(10) stage P1(t+1)->SA       read A-P1[SB]       MFMA mf4-7 x nf0-1
//                 stage N1(t+1)->SA                           MFMA mf4-7 x nf2-3
// FIFO-verified: every part staged >=2 phases before first read; every slot
// freed (last LDS read barrier-separated) before overwrite; waits never 0 in-loop.
#define QMM(MB, NBA) { \
  __builtin_amdgcn_s_setprio(1); \
  _Pragma("unroll") for (int mf_ = 0; mf_ < 4; ++mf_) \
    _Pragma("unroll") for (int nf_ = 0; nf_ < 2; ++nf_) { \
      acc[(MB)+mf_][(NBA)+nf_] = MFMA16(aF[mf_][0], bF[(NBA)+nf_][0], acc[(MB)+mf_][(NBA)+nf_]); \
      acc[(MB)+mf_][(NBA)+nf_] = MFMA16(aF[mf_][1], bF[(NBA)+nf_][1], acc[(MB)+mf_][(NBA)+nf_]); \
    } \
  __builtin_amdgcn_s_setprio(0); }

#define QRDA(SL) \
  _Pragma("unroll") for (int mf_ = 0; mf_ < 4; ++mf_) { \
    aF[mf_][0] = *(const bf16x8*)(rA0 + (SL) * 4096 + mf_ * 1024); \
    aF[mf_][1] = *(const bf16x8*)(rA1 + (SL) * 4096 + mf_ * 1024); }

#define QRDB(SL, NBA) \
  _Pragma("unroll") for (int nf_ = 0; nf_ < 2; ++nf_) { \
    bF[(NBA)+nf_][0] = *(const bf16x8*)(rB0 + (SL) * 8192 + nf_ * 1024); \
    bF[(NBA)+nf_][1] = *(const bf16x8*)(rB1 + (SL) * 8192 + nf_ * 1024); }

#define QSTA(SL, KOFF) \
  async16(pa0 + (KOFF), &As[(SL) * 4096 + tid * 8]); \
  async16(pa1 + (KOFF), &As[(SL) * 4096 + (256 + tid) * 8]);

#define QSTB(SL, NOFF) \
  async16(pb0 + (NOFF), &Bs[(SL) * 8192 + tid * 8]); \
  async16(pb1 + (NOFF), &Bs[(SL) * 8192 + (256 + tid) * 8]); \
  async16(pb2 + (NOFF), &Bs[(SL) * 8192 + (512 + tid) * 8]); \
  async16(pb3 + (NOFF), &Bs[(SL) * 8192 + (768 + tid) * 8]);

#define QTILE(SA, SB, SC) \
  pa0 += 64; pa1 += 64; pb0 += 64; pb1 += 64; pb2 += 64; pb3 += 64; \
  asm volatile("s_waitcnt vmcnt(6)" ::: "memory"); \
  __builtin_amdgcn_s_barrier(); __builtin_amdgcn_sched_barrier(0); \
  QSTA(SC, 0) \
  QRDA(SA) QRDB(SA, 0) \
  QMM(0, 0) \
  asm volatile("s_waitcnt vmcnt(2)" ::: "memory"); \
  __builtin_amdgcn_s_barrier(); __builtin_amdgcn_sched_barrier(0); \
  QSTB(SC, 0) \
  QRDB(SB, 2) \
  QMM(0, 2) \
  asm volatile("s_waitcnt vmcnt(10)" ::: "memory"); \
  __builtin_amdgcn_s_barrier(); __builtin_amdgcn_sched_barrier(0); \
  QSTA(SA, 65536) \
  QRDA(SB) \
  QMM(4, 0) \
  QSTB(SA, 32768) \
  QMM(4, 2)

#define QTAIL(SA, SB) \
  asm volatile("s_waitcnt vmcnt(6)" ::: "memory"); \
  __builtin_amdgcn_s_barrier(); __builtin_amdgcn_sched_barrier(0); \
  QRDA(SA) QRDB(SA, 0) \
  QMM(0, 0) \
  asm volatile("s_waitcnt vmcnt(0)" ::: "memory"); \
  __builtin_amdgcn_s_barrier(); __builtin_amdgcn_sched_barrier(0); \
  QRDB(SB, 2) \
  QMM(0, 2) \
  QRDA(SB) \
  QMM(4, 0) \
  QMM(4, 2)

template <int MODE>
__global__ __launch_bounds__(256, 2) void qg8_k(const u16* __restrict__ A, const u16* __restrict__ WTall,
                                                const float* __restrict__ b0, const float* __restrict__ b1,
                                                const float* __restrict__ b2,
                                                u16* __restrict__ outb, float* __restrict__ outf) {
  __shared__ u16 As[3 * 4096];  // 24KB: A half-parts (64x64)
  __shared__ u16 Bs[3 * 8192];  // 48KB: B half-parts (128x64)
  const int tid = threadIdx.x;
  const int lane = tid & 63;
  const int wn = tid >> 6;       // 4 waves, each owns 64 n-cols, all 128 m-rows
  const int g = lane >> 4, cc = lane & 15;

  // XCD-clustered bijection: xcd owns 8 fixed m-panels of 128 for all nb.
  const int bid = blockIdx.x;
  const int xcd = bid & 7;
  const int idx = bid >> 3;                    // MODE0: 0..95, MODE1: 0..31
  const int m0 = (xcd * 8 + (idx & 7)) * 128;
  const int nb = (idx >> 3) * 256;
  const u16* Bg = WTall + (size_t)(MODE == 0 ? 0 : 3145728) + (size_t)nb * 1024;

  // staging sources (pre-swizzled). A part: unit u = j*256+tid, r=u>>3 (0..63),
  // s=u&7, global row m0+r (+64 for P1 via KOFF), k-chunk s^(r&7).
  const u16* pa0; const u16* pa1;
  const u16* pb0; const u16* pb1; const u16* pb2; const u16* pb3;
  {
    const int u0 = tid, u1 = 256 + tid;
    pa0 = A + (size_t)(m0 + (u0 >> 3)) * 1024 + (((u0 & 7) ^ ((u0 >> 3) & 7)) << 3);
    pa1 = A + (size_t)(m0 + (u1 >> 3)) * 1024 + (((u1 & 7) ^ ((u1 >> 3) & 7)) << 3);
    // B part rows r (0..127) -> global n-row (r>>5)*64 + (r&31) (+32 for N1)
#define BPTR(U) (Bg + (size_t)((((U) >> 8) & 0x7fffffff) * 0 + (((U) >> 3) >> 5) * 64 + (((U) >> 3) & 31)) * 1024 + ((((U) & 7) ^ (((U) >> 3) & 7)) << 3))
    pb0 = BPTR(tid);
    pb1 = BPTR(256 + tid);
    pb2 = BPTR(512 + tid);
    pb3 = BPTR(768 + tid);
#undef BPTR
  }

  // LDS read bases: A row (within part) = mfl*16 + cc; B row = wn*32 + nf*16 + cc.
  // k-chunk kk*4+g at phys slot (kk*4+g)^(cc&7).
  const int s0 = g ^ (cc & 7);
  const u16* rA0 = As + cc * 64 + (s0 << 3);
  const u16* rA1 = As + cc * 64 + ((s0 ^ 4) << 3);
  const u16* rB0 = Bs + (wn * 32 + cc) * 64 + (s0 << 3);
  const u16* rB1 = Bs + (wn * 32 + cc) * 64 + ((s0 ^ 4) << 3);

  f32x4 acc[8][4] = {};
  bf16x8 aF[4][2], bF[4][2];

  // prologue: stage all 4 parts of tile 0 (slots: P0,N0 -> 0; P1,N1 -> 1)
  QSTA(0, 0)
  QSTB(0, 0)
  QSTA(1, 65536)
  QSTB(1, 32768)

  // 15 steady tiles (t=0..14), slots 3-periodic, then tail t=15.
  for (int rep = 0; rep < 5; ++rep) {
    QTILE(0, 1, 2)
    QTILE(2, 0, 1)
    QTILE(1, 2, 0)
  }
  QTAIL(0, 1)

  // epilogue
  const int z = (MODE == 0) ? (nb >> 10) : 0;
  const float* bias = (MODE == 0) ? (z == 0 ? b0 : (z == 1 ? b1 : b2)) : b0;
  const float scl = (MODE == 0 && z == 0) ? 0.18033688011112042f : 1.0f;  // 0.125*log2e

#pragma unroll
  for (int mf = 0; mf < 8; mf++) {
#pragma unroll
    for (int nfa = 0; nfa < 4; nfa++) {
      const int ng = nb + wn * 64 + nfa * 16 + cc;
      const int n = (MODE == 0) ? (ng & 1023) : ng;
      const float bn = bias[n];
      const int mb = m0 + mf * 16 + g * 4;
      if (MODE == 0) {
        u16* o = outb + (size_t)z * 8388608;
        if (z == 2) {
          u16 h[4];
#pragma unroll
          for (int r = 0; r < 4; r++) h[r] = f2bf(acc[mf][nfa][r] + bn);
          const size_t ix = ((size_t)(((mb >> 11) * 16 + (n >> 6)) * 64 + (n & 63))) * 2048 + (mb & 2047);
          *(uint2*)&o[ix] = make_uint2((u32)h[0] | ((u32)h[1] << 16), (u32)h[2] | ((u32)h[3] << 16));
        } else {
#pragma unroll
          for (int r = 0; r < 4; r++) {
            const int m = mb + r;
            const float val = (acc[mf][nfa][r] + bn) * scl;
            o[((size_t)((m >> 11) * 16 + (n >> 6)) * 2048 + (m & 2047)) * 64 + (n & 63)] = f2bf(val);
          }
        }
      } else {
#pragma unroll
        for (int r = 0; r < 4; r++)
          outf[(size_t)(mb + r) * 1024 + n] = acc[mf][nfa][r] + bn;
      }
    }
  }
}

// ---------------- Flash attention (round-14 best: 85.4us, frozen) ----------------
#define SMAX(S0, S1, M, O, PF)                                                \
  {                                                                           \
    float pm_ = max3f(max3f(S0[0], S0[1], S0[2]),                             \
                      max3f(S0[3], S1[0], S1[1]), fmaxf(S1[2], S1[3]));       \
    if (__builtin_expect(!__all(pm_ <= M + 8.0f), 0)) {                       \
      pm_ = fmaxf(pm_, __shfl_xor(pm_, 16));                                  \
      pm_ = fmaxf(pm_, __shfl_xor(pm_, 32));                                  \
      const float mn_ = fmaxf(M, pm_);                                        \
      const float al_ = exp2a(M - mn_);                                       \
      _Pragma("unroll")                                                       \
      for (int r_ = 0; r_ < 4; ++r_) {                                        \
        const float ar_ = __shfl(al_, g * 4 + r_);                            \
        _Pragma("unroll")                                                     \
        for (int t_ = 0; t_ < 5; ++t_) O[t_][r_] *= ar_;                      \
      }                                                                       \
      M = mn_;                                                                \
    }                                                                         \
    const float e0_ = exp2a(S0[0] - M), e1_ = exp2a(S0[1] - M);               \
    const float e2_ = exp2a(S0[2] - M), e3_ = exp2a(S0[3] - M);               \
    const float e4_ = exp2a(S1[0] - M), e5_ = exp2a(S1[1] - M);               \
    const float e6_ = exp2a(S1[2] - M), e7_ = exp2a(S1[3] - M);               \
    union { u32 u[4]; bf16x8 v; } pu_;                                        \
    pu_.u[0] = cvtpk(e0_, e1_); pu_.u[1] = cvtpk(e2_, e3_);                   \
    pu_.u[2] = cvtpk(e4_, e5_); pu_.u[3] = cvtpk(e6_, e7_);                   \
    PF = pu_.v;                                                               \
  }

#define COMPUTE(KB, VB)                                                       \
  _Pragma("unroll")                                                           \
  for (int sub = 0; sub < 2; ++sub) {                                         \
    const u16* pV_ = sub ? pV1 : pV0;                                         \
    bf16x8 k00 = *(const bf16x8*)(pK0 + (KB)*4096 + sub*2048);                \
    bf16x8 k01 = *(const bf16x8*)(pK1 + (KB)*4096 + sub*2048);                \
    bf16x8 k10 = *(const bf16x8*)(pK0 + (KB)*4096 + sub*2048 + 256);          \
    bf16x8 k11 = *(const bf16x8*)(pK1 + (KB)*4096 + sub*2048 + 256);          \
    __builtin_amdgcn_s_setprio(1);                                            \
    f32x4 sA0 = {}, sA1 = {}, sB0 = {}, sB1 = {};                             \
    sA0 = MFMA16(k00, qfA[0], sA0); sA0 = MFMA16(k01, qfA[1], sA0);           \
    sB0 = MFMA16(k00, qfB[0], sB0); sB0 = MFMA16(k01, qfB[1], sB0);           \
    sA1 = MFMA16(k10, qfA[0], sA1); sA1 = MFMA16(k11, qfA[1], sA1);           \
    sB1 = MFMA16(k10, qfB[0], sB1); sB1 = MFMA16(k11, qfB[1], sB1);           \
    __builtin_amdgcn_s_setprio(0);                                            \
    bf16x8 pfA, pfB;                                                          \
    SMAX(sA0, sA1, mA, oA, pfA);                                              \
    SMAX(sB0, sB1, mB, oB, pfB);                                              \
    __builtin_amdgcn_s_setprio(1);                                            \
    _Pragma("unroll")                                                         \
    for (int t = 0; t < 4; ++t) {                                             \
      bf16x8 vf = *(const bf16x8*)(pV_ + (VB)*4096 + t*1024);                 \
      oA[t] = MFMA16(pfA, vf, oA[t]);                                         \
      oB[t] = MFMA16(pfB, vf, oB[t]);                                         \
    }                                                                         \
    oA[4] = MFMA16(pfA, vone, oA[4]);                                         \
    oB[4] = MFMA16(pfB, vone, oB[4]);                                         \
    __builtin_amdgcn_s_setprio(0);                                            \
  }

#define ASTEP(KB, VB, IT, WN, SK, SV, KSB, VSB)                               \
  {                                                                           \
    asm volatile("s_waitcnt vmcnt(" #WN ")" ::: "memory");                    \
    __builtin_amdgcn_s_barrier();                                             \
    __builtin_amdgcn_sched_barrier(0);                                        \
    if (SV) {                                                                 \
      const size_t vo_ = (size_t)((IT) + 1) * 64;                             \
      async16(vS0 + vo_, &Vs[(VSB) * 4096 + tid * 8]);                        \
      async16(vS1 + vo_, &Vs[(VSB) * 4096 + tid * 8 + 2048]);                 \
    }                                                                         \
    if (SK) {                                                                 \
      const size_t ko_ = (size_t)((IT) + 2) * 4096;                           \
      async16(kS0 + ko_, &Ks[(KSB) * 4096 + tid * 8]);                        \
      async16(kS1 + ko_, &Ks[(KSB) * 4096 + tid * 8 + 2048]);                 \
    }                                                                         \
    COMPUTE(KB, VB)                                                           \
  }

__global__ __launch_bounds__(256, 4) void attn_k(const u16* __restrict__ Qg, const u16* __restrict__ Kg,
                                                 const u16* __restrict__ Vtg, u16* __restrict__ ctx) {
  __shared__ u16 Ks[3 * 4096];  // 24KB: K tiles, 3-deep
  __shared__ u16 Vs[2 * 4096];  // 16KB: V tiles, 2-deep
  const int tid = threadIdx.x;
  const int lane = tid & 63;
  const int wid = tid >> 6;
  const int g = lane >> 4, cc = lane & 15;
  const int a_ = cc >> 2, b_ = cc & 3;

  const int bid = blockIdx.x;
  const int xcd = bid & 7, tt = bid >> 3;
  const int bh = xcd * 8 + (tt >> 4);
  const int q0 = (tt & 15) * 128 + wid * 16;
  const size_t base = (size_t)bh * 131072;

  bf16x8 qfA[2], qfB[2];
#pragma unroll
  for (int c2 = 0; c2 < 2; c2++) {
    qfA[c2] = *(const bf16x8*)(Qg + base + (size_t)(q0 + cc) * 64 + c2 * 32 + g * 8);
    qfB[c2] = *(const bf16x8*)(Qg + base + (size_t)(q0 + 64 + cc) * 64 + c2 * 32 + g * 8);
  }

  bf16x8 vone;
#pragma unroll
  for (int j = 0; j < 8; j++) vone[j] = (__bf16)1.0f;

  float mA = -30000.0f, mB = -30000.0f;
  f32x4 oA[5] = {}, oB[5] = {};

  const int cK = b_ | ((a_ & 1) << 2);
  const int slK = g ^ cK;
  const u16* pK0 = &Ks[(8 * a_ + b_) * 64 + (slK << 3)];
  const u16* pK1 = &Ks[(8 * a_ + b_) * 64 + ((slK ^ 4) << 3)];
  const int cV = b_ | (((cc >> 3) & 1) << 2);
  const u16* pV0 = &Vs[cc * 64 + ((g ^ cV) << 3)];
  const u16* pV1 = &Vs[cc * 64 + (((4 + g) ^ cV) << 3)];

  const int r0 = tid >> 3, r1 = r0 + 32;
  const int slot = tid & 7;
  const int sp0 = slot ^ permrow(r0), sp1 = slot ^ permrow(r1);
  const u16* kS0 = Kg + base + (size_t)r0 * 64 + (sp0 << 3);
  const u16* kS1 = Kg + base + (size_t)r1 * 64 + (sp1 << 3);
  const u16* vS0 = Vtg + base + (size_t)r0 * 2048 + (sp0 << 3);
  const u16* vS1 = Vtg + base + (size_t)r1 * 2048 + (sp1 << 3);

  // prologue (FIFO order matters): K0, V0, K1, V1
  async16(kS0, &Ks[tid * 8]);
  async16(kS1, &Ks[tid * 8 + 2048]);
  async16(vS0, &Vs[tid * 8]);
  async16(vS1, &Vs[tid * 8 + 2048]);
  async16(kS0 + 4096, &Ks[4096 + tid * 8]);
  async16(kS1 + 4096, &Ks[4096 + tid * 8 + 2048]);
  async16(vS0 + 64, &Vs[4096 + tid * 8]);
  async16(vS1 + 64, &Vs[4096 + tid * 8 + 2048]);

  ASTEP(0, 0, 0, 4, 1, 0, 2, 0)
  for (int itb = 1; itb <= 19; itb += 6) {
    ASTEP(1, 1, itb + 0, 2, 1, 1, 0, 0)
    ASTEP(2, 0, itb + 1, 2, 1, 1, 1, 1)
    ASTEP(0, 1, itb + 2, 2, 1, 1, 2, 0)
    ASTEP(1, 0, itb + 3, 2, 1, 1, 0, 1)
    ASTEP(2, 1, itb + 4, 2, 1, 1, 1, 0)
    ASTEP(0, 0, itb + 5, 2, 1, 1, 2, 1)
  }
  ASTEP(1, 1, 25, 2, 1, 1, 0, 0)
  ASTEP(2, 0, 26, 2, 1, 1, 1, 1)
  ASTEP(0, 1, 27, 2, 1, 1, 2, 0)
  ASTEP(1, 0, 28, 2, 1, 1, 0, 1)
  ASTEP(2, 1, 29, 2, 1, 1, 1, 0)
  ASTEP(0, 0, 30, 2, 0, 1, 0, 1)   // stage V31 only
  ASTEP(1, 1, 31, 0, 0, 0, 0, 0)   // final drain

  const int b = bh >> 4, h = bh & 15;
#pragma unroll
  for (int r = 0; r < 4; r++) {
    {
      const float inv = __builtin_amdgcn_rcpf(oA[4][r]);
      const int q = q0 + g * 4 + r;
#pragma unroll
      for (int t = 0; t < 4; t++)
        ctx[((size_t)((b * 2048 + q) * 16 + h)) * 64 + t * 16 + cc] = f2bf(oA[t][r] * inv);
    }
    {
      const float inv = __builtin_amdgcn_rcpf(oB[4][r]);
      const int q = q0 + 64 + g * 4 + r;
#pragma unroll
      for (int t = 0; t < 4; t++)
        ctx[((size_t)((b * 2048 + q) * 16 + h)) * 64 + t * 16 + cc] = f2bf(oB[t][r] * inv);
    }
  }
}

extern "C" void kernel_launch(void* const* d_in, const int* in_sizes, int n_in,
                              void* d_out, int out_size, void* d_ws, size_t ws_size,
                              hipStream_t stream) {
  const float* x  = (const float*)d_in[0];
  const float* Wq = (const float*)d_in[1];
  const float* bq = (const float*)d_in[2];
  const float* Wk = (const float*)d_in[3];
  const float* bk = (const float*)d_in[4];
  const float* Wv = (const float*)d_in[5];
  const float* bv = (const float*)d_in[6];
  const float* Wo = (const float*)d_in[7];
  const float* bo = (const float*)d_in[8];
  float* out = (float*)d_out;

  char* w = (char*)d_ws;
  u16* xb   = (u16*)(w);                // 16 MB
  u16* WT   = (u16*)(w + (16u << 20));  //  8 MB
  u16* QKV  = (u16*)(w + (24u << 20));  // 48 MB (Q,K: [bh][t][d]; V: [bh][d][t])
  u16* ctxb = (u16*)(w + (72u << 20));  // 16 MB

  prep_k<<<dim3(12288), dim3(256), 0, stream>>>(x, xb, Wq, Wk, Wv, Wo, WT);
  qg8_k<0><<<dim3(768), dim3(256), 0, stream>>>(xb, WT, bq, bk, bv, QKV, nullptr);
  attn_k<<<dim3(1024), dim3(256), 0, stream>>>(QKV, QKV + 8388608, QKV + 2 * 8388608, ctxb);
  qg8_k<1><<<dim3(256), dim3(256), 0, stream>>>(ctxb, WT, bo, nullptr, nullptr, nullptr, out);
}

// Round 17
// 176.039 us; speedup vs baseline: 1.0405x; 1.0405x over previous
//
#include <hip/hip_runtime.h>
#include <hip/hip_bf16.h>

typedef unsigned short u16;
typedef unsigned int   u32;

typedef __bf16 bf16x8 __attribute__((ext_vector_type(8)));
typedef float  f32x4  __attribute__((ext_vector_type(4)));

#define MFMA16(A, B, C) __builtin_amdgcn_mfma_f32_16x16x32_bf16(A, B, C, 0, 0, 0)

static __device__ __forceinline__ u16 f2bf(float f) {
  union { float f; u32 u; } v; v.f = f;
  u32 r = v.u + 0x7fffu + ((v.u >> 16) & 1u);
  return (u16)(r >> 16);
}

static __device__ __forceinline__ float exp2a(float x) {  // 2^x, raw v_exp_f32
  float r; asm("v_exp_f32 %0, %1" : "=v"(r) : "v"(x)); return r;
}
static __device__ __forceinline__ float max3f(float a, float b, float c) {
  float r; asm("v_max3_f32 %0, %1, %2, %3" : "=v"(r) : "v"(a), "v"(b), "v"(c)); return r;
}
static __device__ __forceinline__ u32 cvtpk(float lo, float hi) {  // {bf16(lo), bf16(hi)}
  u32 r; asm("v_cvt_pk_bf16_f32 %0, %1, %2" : "=v"(r) : "v"(lo), "v"(hi)); return r;
}

static __device__ __forceinline__ void async16(const void* g, void* l) {
  __builtin_amdgcn_global_load_lds((const __attribute__((address_space(1))) void*)g,
                                   (__attribute__((address_space(3))) void*)l, 16, 0, 0);
}

// slot-swizzle involution (16B granularity) for 128B-row LDS tiles
static __device__ __forceinline__ int permrow(int r) {
  return (r & 3) | (((r >> 3) & 1) << 2);
}

// ---------------- prep: x fp32->bf16 (blocks 0..8191) + W transpose (8192..12287) ----
__global__ __launch_bounds__(256) void prep_k(const float* __restrict__ x, u16* __restrict__ xb,
                                              const float* __restrict__ Wq, const float* __restrict__ Wk,
                                              const float* __restrict__ Wv, const float* __restrict__ Wo,
                                              u16* __restrict__ WT) {
  __shared__ float tile[32][33];
  const int bid = blockIdx.x;
  if (bid < 8192) {
    size_t i = ((size_t)bid * 256 + threadIdx.x) * 4;
    float4 v = *(const float4*)(x + i);
    u32 lo = (u32)f2bf(v.x) | ((u32)f2bf(v.y) << 16);
    u32 hi = (u32)f2bf(v.z) | ((u32)f2bf(v.w) << 16);
    *(uint2*)(xb + i) = make_uint2(lo, hi);
  } else {
    const int rem = bid - 8192;
    const int z = rem >> 10;                 // 0..3
    const int rr = rem & 1023;
    const int n0 = (rr & 31) * 32;
    const int k0 = (rr >> 5) * 32;
    const float* W = (z == 0) ? Wq : (z == 1) ? Wk : (z == 2) ? Wv : Wo;
    u16* out = WT + (size_t)z * 1048576;
    const int tx = threadIdx.x & 31, ty = threadIdx.x >> 5;
#pragma unroll
    for (int i = 0; i < 4; i++)
      tile[ty + i * 8][tx] = W[(size_t)(k0 + ty + i * 8) * 1024 + n0 + tx];
    __syncthreads();
#pragma unroll
    for (int i = 0; i < 4; i++)
      out[(size_t)(n0 + ty + i * 8) * 1024 + k0 + tx] = f2bf(tile[tx][ty + i * 8]);
  }
}

// ---------------- GEMM: 256x128 tile, BK=64, counted-vmcnt 3-buffer pipeline ----
// (round-11 proven config, frozen: 8 waves, acc[4][4]; stage 2 tiles ahead;
// vmcnt(6) never 0 in-loop; ONE raw barrier per K-tile; 128B LDS rows with
// XOR slot-swizzle on pre-swizzled source + reads; XCD-clustered 1D grid.)
#define G_STAGE(NXT)                                                          \
  {                                                                           \
    async16(pgA0, &As[(NXT) * 16384 + (0 * 512 + tid) * 8]);                  \
    async16(pgA1, &As[(NXT) * 16384 + (1 * 512 + tid) * 8]);                  \
    async16(pgA2, &As[(NXT) * 16384 + (2 * 512 + tid) * 8]);                  \
    async16(pgA3, &As[(NXT) * 16384 + (3 * 512 + tid) * 8]);                  \
    async16(pgB0, &Bs[(NXT) * 8192 + (0 * 512 + tid) * 8]);                   \
    async16(pgB1, &Bs[(NXT) * 8192 + (1 * 512 + tid) * 8]);                   \
    pgA0 += 64; pgA1 += 64; pgA2 += 64; pgA3 += 64; pgB0 += 64; pgB1 += 64;   \
  }

#define COMPUTE_T(CUR)                                                        \
  _Pragma("unroll")                                                           \
  for (int kk = 0; kk < 2; ++kk) {                                            \
    const u16* pAk = kk ? pA1 : pA0;                                          \
    const u16* pBk = kk ? pB1 : pB0;                                          \
    bf16x8 a0 = *(const bf16x8*)(pAk + (CUR) * 16384);                        \
    bf16x8 a1 = *(const bf16x8*)(pAk + (CUR) * 16384 + 1024);                 \
    bf16x8 a2 = *(const bf16x8*)(pAk + (CUR) * 16384 + 2048);                 \
    bf16x8 a3 = *(const bf16x8*)(pAk + (CUR) * 16384 + 3072);                 \
    bf16x8 b0 = *(const bf16x8*)(pBk + (CUR) * 8192);                         \
    bf16x8 b1 = *(const bf16x8*)(pBk + (CUR) * 8192 + 1024);                  \
    bf16x8 b2 = *(const bf16x8*)(pBk + (CUR) * 8192 + 2048);                  \
    bf16x8 b3 = *(const bf16x8*)(pBk + (CUR) * 8192 + 3072);                  \
    __builtin_amdgcn_s_setprio(1);                                            \
    acc[0][0] = MFMA16(a0, b0, acc[0][0]); acc[0][1] = MFMA16(a0, b1, acc[0][1]); \
    acc[0][2] = MFMA16(a0, b2, acc[0][2]); acc[0][3] = MFMA16(a0, b3, acc[0][3]); \
    acc[1][0] = MFMA16(a1, b0, acc[1][0]); acc[1][1] = MFMA16(a1, b1, acc[1][1]); \
    acc[1][2] = MFMA16(a1, b2, acc[1][2]); acc[1][3] = MFMA16(a1, b3, acc[1][3]); \
    acc[2][0] = MFMA16(a2, b0, acc[2][0]); acc[2][1] = MFMA16(a2, b1, acc[2][1]); \
    acc[2][2] = MFMA16(a2, b2, acc[2][2]); acc[2][3] = MFMA16(a2, b3, acc[2][3]); \
    acc[3][0] = MFMA16(a3, b0, acc[3][0]); acc[3][1] = MFMA16(a3, b1, acc[3][1]); \
    acc[3][2] = MFMA16(a3, b2, acc[3][2]); acc[3][3] = MFMA16(a3, b3, acc[3][3]); \
    __builtin_amdgcn_s_setprio(0);                                            \
  }

#define GITER(CUR, WN, STG, NXT)                                              \
  {                                                                           \
    asm volatile("s_waitcnt vmcnt(" #WN ")" ::: "memory");                    \
    __builtin_amdgcn_s_barrier();                                             \
    __builtin_amdgcn_sched_barrier(0);                                        \
    if (STG) G_STAGE(NXT)                                                     \
    COMPUTE_T(CUR)                                                            \
  }

template <int MODE>
__global__ __launch_bounds__(512, 2) void gemm256_k(const u16* __restrict__ A, const u16* __restrict__ WTall,
                                                    const float* __restrict__ b0, const float* __restrict__ b1,
                                                    const float* __restrict__ b2,
                                                    u16* __restrict__ outb, float* __restrict__ outf) {
  __shared__ u16 As[3 * 16384];  // 3 x 256x64
  __shared__ u16 Bs[3 * 8192];   // 3 x 128x64
  const int tid = threadIdx.x;
  const int lane = tid & 63;
  const int wid = tid >> 6;
  const int wm = wid >> 1, wn = wid & 1;
  const int g = lane >> 4, cc = lane & 15;

  const int bid = blockIdx.x;
  const int xcd = bid & 7;
  const int idx = bid >> 3;
  const int m0 = (xcd * 4 + (idx & 3)) * 256;
  const int nb = (idx >> 2) * 128;
  const u16* Bg = WTall + (size_t)(MODE == 0 ? 0 : 3145728) + (size_t)nb * 1024;

  const u16* pgA0; const u16* pgA1; const u16* pgA2; const u16* pgA3;
  const u16* pgB0; const u16* pgB1;
  {
    const int u0 = tid, u1 = 512 + tid, u2 = 1024 + tid, u3 = 1536 + tid;
    pgA0 = A + (size_t)(m0 + (u0 >> 3)) * 1024 + (((u0 & 7) ^ ((u0 >> 3) & 7)) << 3);
    pgA1 = A + (size_t)(m0 + (u1 >> 3)) * 1024 + (((u1 & 7) ^ ((u1 >> 3) & 7)) << 3);
    pgA2 = A + (size_t)(m0 + (u2 >> 3)) * 1024 + (((u2 & 7) ^ ((u2 >> 3) & 7)) << 3);
    pgA3 = A + (size_t)(m0 + (u3 >> 3)) * 1024 + (((u3 & 7) ^ ((u3 >> 3) & 7)) << 3);
    pgB0 = Bg + (size_t)(u0 >> 3) * 1024 + (((u0 & 7) ^ ((u0 >> 3) & 7)) << 3);
    pgB1 = Bg + (size_t)(u1 >> 3) * 1024 + (((u1 & 7) ^ ((u1 >> 3) & 7)) << 3);
  }

  const int s0 = g ^ (cc & 7);
  const u16* pA0 = As + (wm * 64 + cc) * 64 + (s0 << 3);
  const u16* pA1 = As + (wm * 64 + cc) * 64 + ((s0 ^ 4) << 3);
  const u16* pB0 = Bs + (wn * 64 + cc) * 64 + (s0 << 3);
  const u16* pB1 = Bs + (wn * 64 + cc) * 64 + ((s0 ^ 4) << 3);

  f32x4 acc[4][4] = {};

  G_STAGE(0)
  G_STAGE(1)

  for (int to = 0; to < 12; to += 3) {
    GITER(0, 6, 1, 2)
    GITER(1, 6, 1, 0)
    GITER(2, 6, 1, 1)
  }
  GITER(0, 6, 1, 2)
  GITER(1, 6, 1, 0)
  GITER(2, 6, 0, 0)
  GITER(0, 0, 0, 0)

  const int z = (MODE == 0) ? (nb >> 10) : 0;
  const float* bias = (MODE == 0) ? (z == 0 ? b0 : (z == 1 ? b1 : b2)) : b0;
  const float scl = (MODE == 0 && z == 0) ? 0.18033688011112042f : 1.0f;  // 0.125*log2e

#pragma unroll
  for (int mi = 0; mi < 4; mi++) {
#pragma unroll
    for (int ni = 0; ni < 4; ni++) {
      const int ng = nb + wn * 64 + ni * 16 + cc;
      const int n = (MODE == 0) ? (ng & 1023) : ng;
      const float bn = bias[n];
      const int mb = m0 + wm * 64 + mi * 16 + g * 4;
      if (MODE == 0) {
        u16* o = outb + (size_t)z * 8388608;
        if (z == 2) {
          u16 h[4];
#pragma unroll
          for (int r = 0; r < 4; r++) h[r] = f2bf(acc[mi][ni][r] + bn);
          const size_t ix = ((size_t)(((mb >> 11) * 16 + (n >> 6)) * 64 + (n & 63))) * 2048 + (mb & 2047);
          *(uint2*)&o[ix] = make_uint2((u32)h[0] | ((u32)h[1] << 16), (u32)h[2] | ((u32)h[3] << 16));
        } else {
#pragma unroll
          for (int r = 0; r < 4; r++) {
            const int m = mb + r;
            const float val = (acc[mi][ni][r] + bn) * scl;
            o[((size_t)((m >> 11) * 16 + (n >> 6)) * 2048 + (m & 2047)) * 64 + (n & 63)] = f2bf(val);
          }
        }
      } else {
#pragma unroll
        for (int r = 0; r < 4; r++)
          outf[(size_t)(mb + r) * 1024 + n] = acc[mi][ni][r] + bn;
      }
    }
  }
}

// ---------------- Flash attention: counted-vmcnt pipeline (3-buf K, 2-buf V) ----
// Round-14 best (85.4us): per step vmcnt(2) (never 0 in-loop) -> raw barrier
// -> stage [V(it+1), K(it+2)] -> compute tile it. K ring 3-deep, V ring
// 2-deep; LDS 40KB -> 4 blocks/CU, full 1024-block cohort, zero tail.
#define SMAX(S0, S1, M, O, PF)                                                \
  {                                                                           \
    float pm_ = max3f(max3f(S0[0], S0[1], S0[2]),                             \
                      max3f(S0[3], S1[0], S1[1]), fmaxf(S1[2], S1[3]));       \
    if (__builtin_expect(!__all(pm_ <= M + 8.0f), 0)) {                       \
      pm_ = fmaxf(pm_, __shfl_xor(pm_, 16));                                  \
      pm_ = fmaxf(pm_, __shfl_xor(pm_, 32));                                  \
      const float mn_ = fmaxf(M, pm_);                                        \
      const float al_ = exp2a(M - mn_);                                       \
      _Pragma("unroll")                                                       \
      for (int r_ = 0; r_ < 4; ++r_) {                                        \
        const float ar_ = __shfl(al_, g * 4 + r_);                            \
        _Pragma("unroll")                                                     \
        for (int t_ = 0; t_ < 5; ++t_) O[t_][r_] *= ar_;                      \
      }                                                                       \
      M = mn_;                                                                \
    }                                                                         \
    const float e0_ = exp2a(S0[0] - M), e1_ = exp2a(S0[1] - M);               \
    const float e2_ = exp2a(S0[2] - M), e3_ = exp2a(S0[3] - M);               \
    const float e4_ = exp2a(S1[0] - M), e5_ = exp2a(S1[1] - M);               \
    const float e6_ = exp2a(S1[2] - M), e7_ = exp2a(S1[3] - M);               \
    union { u32 u[4]; bf16x8 v; } pu_;                                        \
    pu_.u[0] = cvtpk(e0_, e1_); pu_.u[1] = cvtpk(e2_, e3_);                   \
    pu_.u[2] = cvtpk(e4_, e5_); pu_.u[3] = cvtpk(e6_, e7_);                   \
    PF = pu_.v;                                                               \
  }

#define COMPUTE(KB, VB)                                                       \
  _Pragma("unroll")                                                           \
  for (int sub = 0; sub < 2; ++sub) {                                         \
    const u16* pV_ = sub ? pV1 : pV0;                                         \
    bf16x8 k00 = *(const bf16x8*)(pK0 + (KB)*4096 + sub*2048);                \
    bf16x8 k01 = *(const bf16x8*)(pK1 + (KB)*4096 + sub*2048);                \
    bf16x8 k10 = *(const bf16x8*)(pK0 + (KB)*4096 + sub*2048 + 256);          \
    bf16x8 k11 = *(const bf16x8*)(pK1 + (KB)*4096 + sub*2048 + 256);          \
    __builtin_amdgcn_s_setprio(1);                                            \
    f32x4 sA0 = {}, sA1 = {}, sB0 = {}, sB1 = {};                             \
    sA0 = MFMA16(k00, qfA[0], sA0); sA0 = MFMA16(k01, qfA[1], sA0);           \
    sB0 = MFMA16(k00, qfB[0], sB0); sB0 = MFMA16(k01, qfB[1], sB0);           \
    sA1 = MFMA16(k10, qfA[0], sA1); sA1 = MFMA16(k11, qfA[1], sA1);           \
    sB1 = MFMA16(k10, qfB[0], sB1); sB1 = MFMA16(k11, qfB[1], sB1);           \
    __builtin_amdgcn_s_setprio(0);                                            \
    bf16x8 pfA, pfB;                                                          \
    SMAX(sA0, sA1, mA, oA, pfA);                                              \
    SMAX(sB0, sB1, mB, oB, pfB);                                              \
    __builtin_amdgcn_s_setprio(1);                                            \
    _Pragma("unroll")                                                         \
    for (int t = 0; t < 4; ++t) {                                             \
      bf16x8 vf = *(const bf16x8*)(pV_ + (VB)*4096 + t*1024);                 \
      oA[t] = MFMA16(pfA, vf, oA[t]);                                         \
      oB[t] = MFMA16(pfB, vf, oB[t]);                                         \
    }                                                                         \
    oA[4] = MFMA16(pfA, vone, oA[4]);                                         \
    oB[4] = MFMA16(pfB, vone, oB[4]);                                         \
    __builtin_amdgcn_s_setprio(0);                                            \
  }

// KB/VB: compute buffers for tile IT. KSB: K-stage buffer for tile IT+2.
// VSB: V-stage buffer for tile IT+1. SK/SV: stage enables. WN: vmcnt arg.
#define ASTEP(KB, VB, IT, WN, SK, SV, KSB, VSB)                               \
  {                                                                           \
    asm volatile("s_waitcnt vmcnt(" #WN ")" ::: "memory");                    \
    __builtin_amdgcn_s_barrier();                                             \
    __builtin_amdgcn_sched_barrier(0);                                        \
    if (SV) {                                                                 \
      const size_t vo_ = (size_t)((IT) + 1) * 64;                             \
      async16(vS0 + vo_, &Vs[(VSB) * 4096 + tid * 8]);                        \
      async16(vS1 + vo_, &Vs[(VSB) * 4096 + tid * 8 + 2048]);                 \
    }                                                                         \
    if (SK) {                                                                 \
      const size_t ko_ = (size_t)((IT) + 2) * 4096;                           \
      async16(kS0 + ko_, &Ks[(KSB) * 4096 + tid * 8]);                        \
      async16(kS1 + ko_, &Ks[(KSB) * 4096 + tid * 8 + 2048]);                 \
    }                                                                         \
    COMPUTE(KB, VB)                                                           \
  }

__global__ __launch_bounds__(256, 4) void attn_k(const u16* __restrict__ Qg, const u16* __restrict__ Kg,
                                                 const u16* __restrict__ Vtg, u16* __restrict__ ctx) {
  __shared__ u16 Ks[3 * 4096];  // 24KB: K tiles, 3-deep
  __shared__ u16 Vs[2 * 4096];  // 16KB: V tiles, 2-deep
  const int tid = threadIdx.x;
  const int lane = tid & 63;
  const int wid = tid >> 6;
  const int g = lane >> 4, cc = lane & 15;
  const int a_ = cc >> 2, b_ = cc & 3;

  const int bid = blockIdx.x;
  const int xcd = bid & 7, tt = bid >> 3;
  const int bh = xcd * 8 + (tt >> 4);
  const int q0 = (tt & 15) * 128 + wid * 16;
  const size_t base = (size_t)bh * 131072;

  bf16x8 qfA[2], qfB[2];
#pragma unroll
  for (int c2 = 0; c2 < 2; c2++) {
    qfA[c2] = *(const bf16x8*)(Qg + base + (size_t)(q0 + cc) * 64 + c2 * 32 + g * 8);
    qfB[c2] = *(const bf16x8*)(Qg + base + (size_t)(q0 + 64 + cc) * 64 + c2 * 32 + g * 8);
  }

  bf16x8 vone;
#pragma unroll
  for (int j = 0; j < 8; j++) vone[j] = (__bf16)1.0f;

  float mA = -30000.0f, mB = -30000.0f;
  f32x4 oA[5] = {}, oB[5] = {};

  const int cK = b_ | ((a_ & 1) << 2);
  const int slK = g ^ cK;
  const u16* pK0 = &Ks[(8 * a_ + b_) * 64 + (slK << 3)];
  const u16* pK1 = &Ks[(8 * a_ + b_) * 64 + ((slK ^ 4) << 3)];
  const int cV = b_ | (((cc >> 3) & 1) << 2);
  const u16* pV0 = &Vs[cc * 64 + ((g ^ cV) << 3)];
  const u16* pV1 = &Vs[cc * 64 + (((4 + g) ^ cV) << 3)];

  const int r0 = tid >> 3, r1 = r0 + 32;
  const int slot = tid & 7;
  const int sp0 = slot ^ permrow(r0), sp1 = slot ^ permrow(r1);
  const u16* kS0 = Kg + base + (size_t)r0 * 64 + (sp0 << 3);
  const u16* kS1 = Kg + base + (size_t)r1 * 64 + (sp1 << 3);
  const u16* vS0 = Vtg + base + (size_t)r0 * 2048 + (sp0 << 3);
  const u16* vS1 = Vtg + base + (size_t)r1 * 2048 + (sp1 << 3);

  // prologue (FIFO order matters): K0, V0, K1, V1
  async16(kS0, &Ks[tid * 8]);
  async16(kS1, &Ks[tid * 8 + 2048]);
  async16(vS0, &Vs[tid * 8]);
  async16(vS1, &Vs[tid * 8 + 2048]);
  async16(kS0 + 4096, &Ks[4096 + tid * 8]);
  async16(kS1 + 4096, &Ks[4096 + tid * 8 + 2048]);
  async16(vS0 + 64, &Vs[4096 + tid * 8]);
  async16(vS1 + 64, &Vs[4096 + tid * 8 + 2048]);

  // it=0: V1 already staged; stage K2->buf2; wait 4 (allow K1,V1 in flight)
  ASTEP(0, 0, 0, 4, 1, 0, 2, 0)
  // it=1..24: steady state, period 6
  for (int itb = 1; itb <= 19; itb += 6) {
    ASTEP(1, 1, itb + 0, 2, 1, 1, 0, 0)
    ASTEP(2, 0, itb + 1, 2, 1, 1, 1, 1)
    ASTEP(0, 1, itb + 2, 2, 1, 1, 2, 0)
    ASTEP(1, 0, itb + 3, 2, 1, 1, 0, 1)
    ASTEP(2, 1, itb + 4, 2, 1, 1, 1, 0)
    ASTEP(0, 0, itb + 5, 2, 1, 1, 2, 1)
  }
  // it=25..31 tail
  ASTEP(1, 1, 25, 2, 1, 1, 0, 0)
  ASTEP(2, 0, 26, 2, 1, 1, 1, 1)
  ASTEP(0, 1, 27, 2, 1, 1, 2, 0)
  ASTEP(1, 0, 28, 2, 1, 1, 0, 1)
  ASTEP(2, 1, 29, 2, 1, 1, 1, 0)
  ASTEP(0, 0, 30, 2, 0, 1, 0, 1)   // stage V31 only
  ASTEP(1, 1, 31, 0, 0, 0, 0, 0)   // final drain

  const int b = bh >> 4, h = bh & 15;
#pragma unroll
  for (int r = 0; r < 4; r++) {
    {
      const float inv = __builtin_amdgcn_rcpf(oA[4][r]);
      const int q = q0 + g * 4 + r;
#pragma unroll
      for (int t = 0; t < 4; t++)
        ctx[((size_t)((b * 2048 + q) * 16 + h)) * 64 + t * 16 + cc] = f2bf(oA[t][r] * inv);
    }
    {
      const float inv = __builtin_amdgcn_rcpf(oB[4][r]);
      const int q = q0 + 64 + g * 4 + r;
#pragma unroll
      for (int t = 0; t < 4; t++)
        ctx[((size_t)((b * 2048 + q) * 16 + h)) * 64 + t * 16 + cc] = f2bf(oB[t][r] * inv);
    }
  }
}

extern "C" void kernel_launch(void* const* d_in, const int* in_sizes, int n_in,
                              void* d_out, int out_size, void* d_ws, size_t ws_size,
                              hipStream_t stream) {
  const float* x  = (const float*)d_in[0];
  const float* Wq = (const float*)d_in[1];
  const float* bq = (const float*)d_in[2];
  const float* Wk = (const float*)d_in[3];
  const float* bk = (const float*)d_in[4];
  const float* Wv = (const float*)d_in[5];
  const float* bv = (const float*)d_in[6];
  const float* Wo = (const float*)d_in[7];
  const float* bo = (const float*)d_in[8];
  float* out = (float*)d_out;

  char* w = (char*)d_ws;
  u16* xb   = (u16*)(w);                // 16 MB
  u16* WT   = (u16*)(w + (16u << 20));  //  8 MB
  u16* QKV  = (u16*)(w + (24u << 20));  // 48 MB (Q,K: [bh][t][d]; V: [bh][d][t])
  u16* ctxb = (u16*)(w + (72u << 20));  // 16 MB

  prep_k<<<dim3(12288), dim3(256), 0, stream>>>(x, xb, Wq, Wk, Wv, Wo, WT);
  gemm256_k<0><<<dim3(768), dim3(512), 0, stream>>>(xb, WT, bq, bk, bv, QKV, nullptr);
  attn_k<<<dim3(1024), dim3(256), 0, stream>>>(QKV, QKV + 8388608, QKV + 2 * 8388608, ctxb);
  gemm256_k<1><<<dim3(256), dim3(512), 0, stream>>>(ctxb, WT, bo, nullptr, nullptr, nullptr, out);
}